// Round 7
// baseline (2638.365 us; speedup 1.0000x reference)
//
#include <hip/hip_runtime.h>
#include <cstdint>
#include <cstddef>

typedef unsigned short ushort_t;
typedef unsigned int uint_t;
typedef unsigned long long u64_t;
typedef __attribute__((ext_vector_type(8))) short frag16;
typedef __attribute__((ext_vector_type(8))) unsigned short u16x8;
typedef __attribute__((ext_vector_type(4))) float f32x4;

#define SEQ   512
#define INF   512
#define HID   1024
#define OUTF  512
#define NB     4    // batches per group
#define RPB    64   // W_hh rows (output cols) per block
#define WSTR   1040 // LDS row stride (ushorts)
#define SPIN_LIMIT (1 << 18)

__device__ __forceinline__ float b2f(ushort_t u) {
    union { unsigned int i; float f; } v; v.i = ((unsigned int)u) << 16; return v.f;
}
__device__ __forceinline__ ushort_t f2b(float f) {  // RNE fp32->bf16
    unsigned int u = __float_as_uint(f);
    unsigned int r = (u + 0x7fffu + ((u >> 16) & 1u)) >> 16;
    return (ushort_t)r;
}
__device__ __forceinline__ float fast_tanh(float s) {
    const float e = __expf(2.0f * s);
    return 1.0f - 2.0f * __builtin_amdgcn_rcpf(e + 1.0f);
}

// LDS-only barrier (no vmcnt drain: in-flight global stores/loads stay in flight).
__device__ __forceinline__ void lds_barrier() {
    asm volatile("s_waitcnt lgkmcnt(0)" ::: "memory");
    __builtin_amdgcn_sched_barrier(0);
    __builtin_amdgcn_s_barrier();
    __builtin_amdgcn_sched_barrier(0);
}

__device__ __forceinline__ void cvt8_hilo(const float* __restrict__ src, u16x8* hi, u16x8* lo) {
    const float4 x0 = *(const float4*)src;
    const float4 x1 = *(const float4*)(src + 4);
    float xs[8] = {x0.x,x0.y,x0.z,x0.w,x1.x,x1.y,x1.z,x1.w};
    u16x8 h, l;
#pragma unroll
    for (int j = 0; j < 8; ++j) {
        const ushort_t hb = f2b(xs[j]);
        h[j] = hb;
        l[j] = f2b(xs[j] - b2f(hb));
    }
    *hi = h; if (lo) *lo = l;
}
__device__ __forceinline__ u16x8 cvt8_hi(const float* __restrict__ src) {
    const float4 x0 = *(const float4*)src;
    const float4 x1 = *(const float4*)(src + 4);
    float xs[8] = {x0.x,x0.y,x0.z,x0.w,x1.x,x1.y,x1.z,x1.w};
    u16x8 h;
#pragma unroll
    for (int j = 0; j < 8; ++j) h[j] = f2b(xs[j]);
    return h;
}

// ---------------- Phase 1: XP[m][n] = sum_k X[m,k]*Wih[n,k] + bih[n] + bhh[n] ----
__global__ __launch_bounds__(256, 2)
void xproj_kernel(const float* __restrict__ X, const float* __restrict__ Wih,
                  const float* __restrict__ bih, const float* __restrict__ bhh,
                  float* __restrict__ XP)
{
    __shared__ ushort_t Ah[128][40];
    __shared__ ushort_t Al[128][40];
    __shared__ ushort_t Bs[128][40];
    const int tid = (int)threadIdx.x;
    const int m0 = (int)blockIdx.x * 128;
    const int n0 = (int)blockIdx.y * 128;
    const int w  = tid >> 6, l = tid & 63;
    const int wm = (w & 1) * 64, wn = (w >> 1) * 64;
    const int lm = l & 15, lg = l >> 4, hk = lg * 8;
    const int sr = tid >> 2, sc = (tid & 3) * 8;

    f32x4 acc[4][4];
#pragma unroll
    for (int a = 0; a < 4; ++a)
#pragma unroll
        for (int b = 0; b < 4; ++b) { acc[a][b][0]=0.f; acc[a][b][1]=0.f; acc[a][b][2]=0.f; acc[a][b][3]=0.f; }

    for (int ko = 0; ko < INF; ko += 32) {
        __syncthreads();
        u16x8 h, lo;
        cvt8_hilo(&X[(size_t)(m0+sr)*INF + ko + sc], &h, &lo);
        *(u16x8*)&Ah[sr][sc] = h;  *(u16x8*)&Al[sr][sc] = lo;
        cvt8_hilo(&X[(size_t)(m0+sr+64)*INF + ko + sc], &h, &lo);
        *(u16x8*)&Ah[sr+64][sc] = h;  *(u16x8*)&Al[sr+64][sc] = lo;
        *(u16x8*)&Bs[sr][sc]    = cvt8_hi(&Wih[(size_t)(n0+sr)*INF + ko + sc]);
        *(u16x8*)&Bs[sr+64][sc] = cvt8_hi(&Wih[(size_t)(n0+sr+64)*INF + ko + sc]);
        __syncthreads();
        frag16 afh[4], afl[4], bf[4];
#pragma unroll
        for (int i = 0; i < 4; ++i) afh[i] = *(const frag16*)&Ah[wm + i*16 + lm][hk];
#pragma unroll
        for (int i = 0; i < 4; ++i) afl[i] = *(const frag16*)&Al[wm + i*16 + lm][hk];
#pragma unroll
        for (int i = 0; i < 4; ++i) bf[i]  = *(const frag16*)&Bs[wn + i*16 + lm][hk];
#pragma unroll
        for (int a = 0; a < 4; ++a)
#pragma unroll
            for (int b = 0; b < 4; ++b) {
                acc[a][b] = __builtin_amdgcn_mfma_f32_16x16x32_bf16(afh[a], bf[b], acc[a][b], 0, 0, 0);
                acc[a][b] = __builtin_amdgcn_mfma_f32_16x16x32_bf16(afl[a], bf[b], acc[a][b], 0, 0, 0);
            }
    }

#pragma unroll
    for (int b = 0; b < 4; ++b) {
        const int n = n0 + wn + b*16 + lm;
        const float bias = bih[n] + bhh[n];
#pragma unroll
        for (int a = 0; a < 4; ++a)
#pragma unroll
            for (int q = 0; q < 4; ++q) {
                const int m = m0 + wm + a*16 + lg*4 + q;
                XP[(size_t)m * HID + n] = acc[a][b][q] + bias;
            }
    }
}

// ---------------- Phase 2: persistent scan, tagged-data exchange ---------------
// Protocol (proven, round-3): h travels as one 8-byte agent-scope relaxed
// atomic word (packed_bf16hi|lo << 32) | (t+1); data is its own ready flag;
// ping-pong (R=2) safe by spin-gating (skew <= 1 step). A block stores tag t+1
// only after its pre-finish barrier, which joins all 4 waves, whose
// quarter-spins collectively covered all 16 group-mates' tag-t words.
//
// V7 (resubmitted verbatim — round-6 bench was an infra failure, no data):
// round-3 structure, heater removed (round-5 killed the clock theory), spin
// replaced with PIPELINED 2-GENERATION polling: issue gen-B loads, then check
// gen-A (counted vmcnt since gen-B is outstanding), alternate. Poll period
// drops from ~RT+check to ~RT/2; detection lag after tag arrival drops from
// ~1.5-2.5 RT to ~1.1-1.3 RT. Exit requires one COMPLETE generation fully
// tagged -> same certification property; stale in-flight loads of the other
// generation are discarded. Static ping-pong (no runtime-indexed arrays ->
// no scratch, rule #20). Spin stays SPIN_LIMIT-bounded (hang-proof).
__global__ __launch_bounds__(256, 1)
void rnn_scan_kernel(const float* __restrict__ XP, const float* __restrict__ Whh,
                     u64_t* __restrict__ Hbuf)
{
    __shared__ ushort_t Ws[RPB][WSTR];        // 133,120 B
    __shared__ ushort_t Hhi[NB][WSTR];        //   8,320 B
    __shared__ ushort_t Hlo[NB][WSTR];        //   8,320 B
    __shared__ float    Cred[2][4][4][4][16]; //   8,192 B -> 157,952 B total

    const int tid = (int)threadIdx.x;
    const int w = tid >> 6, l = tid & 63;     // wave, lane
    const int lm = l & 15, lg = l >> 4;
    const int bid = (int)blockIdx.x;
    const int gid = (bid & 7) * 2 + ((bid >> 3) & 1);
    const int r   = bid >> 4;
    const int b0 = gid * NB;
    const int j0 = r * RPB;
    const int qcol = w * 256;                 // this wave's K-quarter
    const int jcol = j0 + w*16 + lm;          // this lane's finish column
    const int bq   = b0 + lg;                 // this lane's finish batch

    // Load this block's 64 W_hh rows into LDS as bf16 (once).
    {
        const int rr = tid >> 2, cq = (tid & 3) * 256;
        const float* src = Whh + (size_t)(j0 + rr) * HID + cq;
#pragma unroll
        for (int i = 0; i < 32; ++i)
            *(u16x8*)&Ws[rr][cq + i*8] = cvt8_hi(&src[i*8]);
    }
    lds_barrier();

    // per-lane gather offsets: word j = row b0+(j&3), col qcol+(j>>2)*64+l
    int goff[16];
#pragma unroll
    for (int j = 0; j < 16; ++j)
        goff[j] = (b0 + (j & 3)) * 1024 + qcol + ((j >> 2) << 6) + l;

    u64_t v[16];   // gather generation A (live across iterations; pre-issued)
    float xpv, xpn;

    // ---- t = 0: h0 = tanh(xp); pre-issue gen-A gather for t=1; store tag 1 ----
    {
        xpv = XP[(size_t)((bq) * SEQ + 0) * HID + jcol];
        const float hv = fast_tanh(xpv);
        const ushort_t hi = f2b(hv);
        const ushort_t lo = f2b(hv - b2f(hi));
        const u64_t pk = ((u64_t)((uint_t)hi | ((uint_t)lo << 16)) << 32) | 1ull;
#pragma unroll
        for (int j = 0; j < 16; ++j)
            v[j] = __hip_atomic_load(&Hbuf[goff[j]], __ATOMIC_RELAXED,
                                     __HIP_MEMORY_SCOPE_AGENT);
        xpn = XP[(size_t)((bq) * SEQ + 1) * HID + jcol];
        __hip_atomic_store(&Hbuf[(size_t)bq * 1024 + jcol], pk,
                           __ATOMIC_RELAXED, __HIP_MEMORY_SCOPE_AGENT);
    }

    for (int t = 1; t < SEQ; ++t) {
        xpv = xpn;
        // ---- pipelined 2-gen spin on the quarter gather ----
        {
            const u64_t* base = Hbuf + (size_t)((t - 1) & 1) * 65536;
            const uint_t want = (uint_t)t;
            u64_t vb[16];
            int spin = 0;
            for (;;) {
                // issue gen B (keeps a generation in flight past the check)
#pragma unroll
                for (int j = 0; j < 16; ++j)
                    vb[j] = __hip_atomic_load(&base[goff[j]], __ATOMIC_RELAXED,
                                              __HIP_MEMORY_SCOPE_AGENT);
                // check gen A (counted vmcnt: only gen-A loads must be done)
                int bad = 0;
#pragma unroll
                for (int j = 0; j < 16; ++j) bad |= ((uint_t)v[j] != want);
                if (!__any(bad)) break;               // v[] holds the data
                if (++spin > SPIN_LIMIT) break;       // hang-proof: finite-wrong
                // issue gen A again
#pragma unroll
                for (int j = 0; j < 16; ++j)
                    v[j] = __hip_atomic_load(&base[goff[j]], __ATOMIC_RELAXED,
                                             __HIP_MEMORY_SCOPE_AGENT);
                // check gen B
                bad = 0;
#pragma unroll
                for (int j = 0; j < 16; ++j) bad |= ((uint_t)vb[j] != want);
                if (!__any(bad)) {
#pragma unroll
                    for (int j = 0; j < 16; ++j) v[j] = vb[j];   // consume B
                    break;
                }
                if (++spin > SPIN_LIMIT) break;
            }
        }

        // ---- stage own quarter into hi/lo planes (wave-private cols) ----
#pragma unroll
        for (int j = 0; j < 16; ++j) {
            const uint_t d = (uint_t)(v[j] >> 32);
            const int c = qcol + ((j >> 2) << 6) + l;
            Hhi[j & 3][c] = (ushort_t)(d & 0xffffu);
            Hlo[j & 3][c] = (ushort_t)(d >> 16);
        }
        asm volatile("s_waitcnt lgkmcnt(0)" ::: "memory");
        __builtin_amdgcn_sched_barrier(0);

        // ---- MFMA: wave w does K-quarter [256w,256w+256), 4 col-tiles ----
        f32x4 acc[4];
#pragma unroll
        for (int i = 0; i < 4; ++i) { acc[i][0]=0.f; acc[i][1]=0.f; acc[i][2]=0.f; acc[i][3]=0.f; }
        {
            const int kbase = qcol + lg * 8;
            const ushort_t* ph = &Hhi[lm & 3][kbase];
            const ushort_t* pl = &Hlo[lm & 3][kbase];
            const ushort_t* pw = &Ws[lm][kbase];
#pragma unroll
            for (int kk = 0; kk < 256; kk += 32) {
                const frag16 ahi = *(const frag16*)(ph + kk);
                const frag16 alo = *(const frag16*)(pl + kk);
#pragma unroll
                for (int tl = 0; tl < 4; ++tl) {
                    const frag16 wf = *(const frag16*)(pw + (size_t)tl * 16 * WSTR + kk);
                    acc[tl] = __builtin_amdgcn_mfma_f32_16x16x32_bf16(ahi, wf, acc[tl], 0, 0, 0);
                    acc[tl] = __builtin_amdgcn_mfma_f32_16x16x32_bf16(alo, wf, acc[tl], 0, 0, 0);
                }
            }
        }
        // acc rows are batch-replicated across lg (row=lg*4+q => batch q):
        // lane(lm,lg) writes tile tl=lg -> 4 LDS writes/lane.
#pragma unroll
        for (int q = 0; q < 4; ++q)
            Cred[t & 1][w][lg][q][lm] = acc[lg][q];
        lds_barrier();

        // ---- finish: all 64 lanes; lane(lm,lg) owns (batch bq, col jcol) ----
        const float s = (Cred[t & 1][0][w][lg][lm] + Cred[t & 1][1][w][lg][lm])
                      + (Cred[t & 1][2][w][lg][lm] + Cred[t & 1][3][w][lg][lm]);
        const float hv = fast_tanh(s + xpv);
        const ushort_t hi = f2b(hv);
        const ushort_t lo = f2b(hv - b2f(hi));
        const u64_t pk = ((u64_t)((uint_t)hi | ((uint_t)lo << 16)) << 32)
                       | (u64_t)(uint_t)(t + 1);   // tag t+1, never 0

        // ---- pre-issue next-step gen-A gather + XP BEFORE the store ----
        if (t + 1 < SEQ) {
            const u64_t* base = Hbuf + (size_t)(t & 1) * 65536;
#pragma unroll
            for (int j = 0; j < 16; ++j)
                v[j] = __hip_atomic_load(&base[goff[j]], __ATOMIC_RELAXED,
                                         __HIP_MEMORY_SCOPE_AGENT);
            xpn = XP[(size_t)((bq) * SEQ + (t + 1)) * HID + jcol];
        }
        __hip_atomic_store(&Hbuf[((size_t)(t & 1) * 64 + bq) * 1024 + jcol], pk,
                           __ATOMIC_RELAXED, __HIP_MEMORY_SCOPE_AGENT);
        // no trailing barrier: stage writes are wave-private, Cred is
        // ping-ponged by t&1, global slot reuse is gated by the spin.
    }
}

// ---------------- Phase 3: Out[b][n] = sum_k H[b,k]*Who[n,k] + bho[n] ----------
__global__ __launch_bounds__(256)
void outproj_kernel(const u64_t* __restrict__ Hp, const float* __restrict__ Who,
                    const float* __restrict__ bho, float* __restrict__ Out)
{
    const int tid = (int)threadIdx.x;
    const int w = tid >> 6, l = tid & 63;
    const int lm = l & 15, lg = l >> 4, hk = lg * 8;
    const int n0 = (int)blockIdx.x * 64;

    f32x4 acc[4];
#pragma unroll
    for (int i = 0; i < 4; ++i) { acc[i][0]=0.f; acc[i][1]=0.f; acc[i][2]=0.f; acc[i][3]=0.f; }

    for (int k0 = 0; k0 < HID; k0 += 32) {
        const u64_t* hr = Hp + (size_t)(w*16 + lm) * HID + k0 + hk;
        frag16 ahi, alo;
#pragma unroll
        for (int j = 0; j < 8; ++j) {
            const uint_t d = (uint_t)(hr[j] >> 32);
            ahi[j] = (short)(d & 0xffffu);
            alo[j] = (short)(d >> 16);
        }
#pragma unroll
        for (int bi = 0; bi < 4; ++bi) {
            const u16x8 bv = cvt8_hi(&Who[(size_t)(n0 + bi*16 + lm) * HID + k0 + hk]);
            acc[bi] = __builtin_amdgcn_mfma_f32_16x16x32_bf16(ahi, (frag16)bv, acc[bi], 0, 0, 0);
            acc[bi] = __builtin_amdgcn_mfma_f32_16x16x32_bf16(alo, (frag16)bv, acc[bi], 0, 0, 0);
        }
    }
#pragma unroll
    for (int bi = 0; bi < 4; ++bi) {
        const int n = n0 + bi*16 + lm;
        const float bias = bho[n];
#pragma unroll
        for (int q = 0; q < 4; ++q) {
            const int b = w*16 + lg*4 + q;
            Out[(size_t)b * OUTF + n] = acc[bi][q] + bias;
        }
    }
}

// ---------------- launcher -----------------------------------------------------
extern "C" void kernel_launch(void* const* d_in, const int* in_sizes, int n_in,
                              void* d_out, int out_size, void* d_ws, size_t ws_size,
                              hipStream_t stream)
{
    const float* X   = (const float*)d_in[0];
    const float* Wih = (const float*)d_in[1];
    const float* bih = (const float*)d_in[2];
    const float* Whh = (const float*)d_in[3];
    const float* bhh = (const float*)d_in[4];
    const float* Who = (const float*)d_in[5];
    const float* bho = (const float*)d_in[6];
    float* Out = (float*)d_out;

    char* ws = (char*)d_ws;
    float* XP = (float*)ws;                                        // 128 MiB
    u64_t* Hbuf = (u64_t*)(ws + (size_t)32768 * 1024 * 4);         // 1 MiB
    // No memset needed: tags are t+1 (1..512); 0xAA-poison and zeros never match.

    xproj_kernel<<<dim3(256, 8), dim3(256), 0, stream>>>(X, Wih, bih, bhh, XP);

    rnn_scan_kernel<<<dim3(256), dim3(256), 0, stream>>>(XP, Whh, Hbuf);

    // SEQ=512 -> final step t=511 wrote buffer (511 & 1) = 1
    outproj_kernel<<<dim3(OUTF / 64), dim3(256), 0, stream>>>(Hbuf + (size_t)64 * 1024,
                                                              Who, bho, Out);
}

// Round 8
// 1848.503 us; speedup vs baseline: 1.4273x; 1.4273x over previous
//
#include <hip/hip_runtime.h>
#include <cstdint>
#include <cstddef>

typedef unsigned short ushort_t;
typedef unsigned int uint_t;
typedef unsigned long long u64_t;
typedef __attribute__((ext_vector_type(8))) short frag16;
typedef __attribute__((ext_vector_type(8))) unsigned short u16x8;
typedef __attribute__((ext_vector_type(4))) float f32x4;

#define SEQ   512
#define INF   512
#define HID   1024
#define OUTF  512
#define NB     4    // batches per group
#define RPB    64   // W_hh rows (output cols) per block
#define WSTR   1040 // LDS row stride (ushorts)
#define SPIN_LIMIT (1 << 18)

__device__ __forceinline__ float b2f(ushort_t u) {
    union { unsigned int i; float f; } v; v.i = ((unsigned int)u) << 16; return v.f;
}
__device__ __forceinline__ ushort_t f2b(float f) {  // RNE fp32->bf16
    unsigned int u = __float_as_uint(f);
    unsigned int r = (u + 0x7fffu + ((u >> 16) & 1u)) >> 16;
    return (ushort_t)r;
}
__device__ __forceinline__ float fast_tanh(float s) {
    const float e = __expf(2.0f * s);
    return 1.0f - 2.0f * __builtin_amdgcn_rcpf(e + 1.0f);
}

// LDS-only barrier (no vmcnt drain: in-flight global stores/loads stay in flight).
__device__ __forceinline__ void lds_barrier() {
    asm volatile("s_waitcnt lgkmcnt(0)" ::: "memory");
    __builtin_amdgcn_sched_barrier(0);
    __builtin_amdgcn_s_barrier();
    __builtin_amdgcn_sched_barrier(0);
}

__device__ __forceinline__ void cvt8_hilo(const float* __restrict__ src, u16x8* hi, u16x8* lo) {
    const float4 x0 = *(const float4*)src;
    const float4 x1 = *(const float4*)(src + 4);
    float xs[8] = {x0.x,x0.y,x0.z,x0.w,x1.x,x1.y,x1.z,x1.w};
    u16x8 h, l;
#pragma unroll
    for (int j = 0; j < 8; ++j) {
        const ushort_t hb = f2b(xs[j]);
        h[j] = hb;
        l[j] = f2b(xs[j] - b2f(hb));
    }
    *hi = h; if (lo) *lo = l;
}
__device__ __forceinline__ u16x8 cvt8_hi(const float* __restrict__ src) {
    const float4 x0 = *(const float4*)src;
    const float4 x1 = *(const float4*)(src + 4);
    float xs[8] = {x0.x,x0.y,x0.z,x0.w,x1.x,x1.y,x1.z,x1.w};
    u16x8 h;
#pragma unroll
    for (int j = 0; j < 8; ++j) h[j] = f2b(xs[j]);
    return h;
}

// ---------------- Phase 1: XP[m][n] = sum_k X[m,k]*Wih[n,k] + bih[n] + bhh[n] ----
__global__ __launch_bounds__(256, 2)
void xproj_kernel(const float* __restrict__ X, const float* __restrict__ Wih,
                  const float* __restrict__ bih, const float* __restrict__ bhh,
                  float* __restrict__ XP)
{
    __shared__ ushort_t Ah[128][40];
    __shared__ ushort_t Al[128][40];
    __shared__ ushort_t Bs[128][40];
    const int tid = (int)threadIdx.x;
    const int m0 = (int)blockIdx.x * 128;
    const int n0 = (int)blockIdx.y * 128;
    const int w  = tid >> 6, l = tid & 63;
    const int wm = (w & 1) * 64, wn = (w >> 1) * 64;
    const int lm = l & 15, lg = l >> 4, hk = lg * 8;
    const int sr = tid >> 2, sc = (tid & 3) * 8;

    f32x4 acc[4][4];
#pragma unroll
    for (int a = 0; a < 4; ++a)
#pragma unroll
        for (int b = 0; b < 4; ++b) { acc[a][b][0]=0.f; acc[a][b][1]=0.f; acc[a][b][2]=0.f; acc[a][b][3]=0.f; }

    for (int ko = 0; ko < INF; ko += 32) {
        __syncthreads();
        u16x8 h, lo;
        cvt8_hilo(&X[(size_t)(m0+sr)*INF + ko + sc], &h, &lo);
        *(u16x8*)&Ah[sr][sc] = h;  *(u16x8*)&Al[sr][sc] = lo;
        cvt8_hilo(&X[(size_t)(m0+sr+64)*INF + ko + sc], &h, &lo);
        *(u16x8*)&Ah[sr+64][sc] = h;  *(u16x8*)&Al[sr+64][sc] = lo;
        *(u16x8*)&Bs[sr][sc]    = cvt8_hi(&Wih[(size_t)(n0+sr)*INF + ko + sc]);
        *(u16x8*)&Bs[sr+64][sc] = cvt8_hi(&Wih[(size_t)(n0+sr+64)*INF + ko + sc]);
        __syncthreads();
        frag16 afh[4], afl[4], bf[4];
#pragma unroll
        for (int i = 0; i < 4; ++i) afh[i] = *(const frag16*)&Ah[wm + i*16 + lm][hk];
#pragma unroll
        for (int i = 0; i < 4; ++i) afl[i] = *(const frag16*)&Al[wm + i*16 + lm][hk];
#pragma unroll
        for (int i = 0; i < 4; ++i) bf[i]  = *(const frag16*)&Bs[wn + i*16 + lm][hk];
#pragma unroll
        for (int a = 0; a < 4; ++a)
#pragma unroll
            for (int b = 0; b < 4; ++b) {
                acc[a][b] = __builtin_amdgcn_mfma_f32_16x16x32_bf16(afh[a], bf[b], acc[a][b], 0, 0, 0);
                acc[a][b] = __builtin_amdgcn_mfma_f32_16x16x32_bf16(afl[a], bf[b], acc[a][b], 0, 0, 0);
            }
    }

#pragma unroll
    for (int b = 0; b < 4; ++b) {
        const int n = n0 + wn + b*16 + lm;
        const float bias = bih[n] + bhh[n];
#pragma unroll
        for (int a = 0; a < 4; ++a)
#pragma unroll
            for (int q = 0; q < 4; ++q) {
                const int m = m0 + wm + a*16 + lg*4 + q;
                XP[(size_t)m * HID + n] = acc[a][b][q] + bias;
            }
    }
}

// ---------------- Phase 2: persistent scan, tagged-data exchange ---------------
// Protocol: h travels as one 4-BYTE agent-scope relaxed atomic word
// (bf16(h) << 16) | (t+1); data is its own ready flag (tags 1..512 fit 16
// bits; 0xAAAA-poison and zeros never match). Ping-pong (R=2) safe by
// spin-gating (skew <= 1 step): a block stores tag t+1 only after its
// pre-finish barrier, which joins all 4 waves, whose quarter-spins
// collectively covered all 16 group-mates' tag-t words.
//
// V8: R3 structure (best measured: 1864us) with the exchange payload halved
// 8B -> 4B. Poll-intensity ledger across R1/R2/R3/R7 is monotone: more poll
// traffic on the exchange lines = slower (R7's 2x unconditional polling:
// +30%) -> live model is contention at the coherency point, where poll reads
// delay the very stores they await. 4B words halve store bytes, poll bytes,
// and line occupancy; dropping the lo-half also halves the compute path
// (16 MFMAs/wave/step, half the stage writes and A-frag reads). Cost: h
// propagates at bf16 precision (W_hh is already bf16 in LDS; absmax headroom
// 0.0039 vs 0.0275). Spin = R3's conditional-reload form exactly.
__global__ __launch_bounds__(256, 1)
void rnn_scan_kernel(const float* __restrict__ XP, const float* __restrict__ Whh,
                     uint_t* __restrict__ Hbuf)
{
    __shared__ ushort_t Ws[RPB][WSTR];        // 133,120 B
    __shared__ ushort_t Hhi[NB][WSTR];        //   8,320 B
    __shared__ float    Cred[2][4][4][4][16]; //   8,192 B -> 149,632 B total

    const int tid = (int)threadIdx.x;
    const int w = tid >> 6, l = tid & 63;     // wave, lane
    const int lm = l & 15, lg = l >> 4;
    const int bid = (int)blockIdx.x;
    const int gid = (bid & 7) * 2 + ((bid >> 3) & 1);  // same-XCD grouping (R3)
    const int r   = bid >> 4;
    const int b0 = gid * NB;
    const int j0 = r * RPB;
    const int qcol = w * 256;                 // this wave's K-quarter
    const int jcol = j0 + w*16 + lm;          // this lane's finish column
    const int bq   = b0 + lg;                 // this lane's finish batch

    // Load this block's 64 W_hh rows into LDS as bf16 (once).
    {
        const int rr = tid >> 2, cq = (tid & 3) * 256;
        const float* src = Whh + (size_t)(j0 + rr) * HID + cq;
#pragma unroll
        for (int i = 0; i < 32; ++i)
            *(u16x8*)&Ws[rr][cq + i*8] = cvt8_hi(&src[i*8]);
    }
    lds_barrier();

    // per-lane gather offsets: word j = row b0+(j&3), col qcol+(j>>2)*64+l
    int goff[16];
#pragma unroll
    for (int j = 0; j < 16; ++j)
        goff[j] = (b0 + (j & 3)) * 1024 + qcol + ((j >> 2) << 6) + l;

    uint_t v[16];  // in-flight gather words (live across iterations)
    float xpv, xpn;

    // ---- t = 0: h0 = tanh(xp); pre-issue gather for t=1; store tag 1 ----
    {
        xpv = XP[(size_t)((bq) * SEQ + 0) * HID + jcol];
        const float hv = fast_tanh(xpv);
        const uint_t pk = ((uint_t)f2b(hv) << 16) | 1u;
#pragma unroll
        for (int j = 0; j < 16; ++j)
            v[j] = __hip_atomic_load(&Hbuf[goff[j]], __ATOMIC_RELAXED,
                                     __HIP_MEMORY_SCOPE_AGENT);
        xpn = XP[(size_t)((bq) * SEQ + 1) * HID + jcol];
        __hip_atomic_store(&Hbuf[(size_t)bq * 1024 + jcol], pk,
                           __ATOMIC_RELAXED, __HIP_MEMORY_SCOPE_AGENT);
    }

    for (int t = 1; t < SEQ; ++t) {
        xpv = xpn;
        // ---- spin on pre-issued quarter gather (R3 conditional-reload form) ----
        {
            const uint_t* base = Hbuf + (size_t)((t - 1) & 1) * 65536;
            const uint_t want = (uint_t)t;     // tag written at step t-1
            int spin = 0;
            for (;;) {
                int bad = 0;
#pragma unroll
                for (int j = 0; j < 16; ++j) bad |= ((v[j] & 0xffffu) != want);
                if (!__any(bad)) break;
                if (++spin > SPIN_LIMIT) break;   // hang-proof: finite-wrong
#pragma unroll
                for (int j = 0; j < 16; ++j)
                    if ((v[j] & 0xffffu) != want)
                        v[j] = __hip_atomic_load(&base[goff[j]], __ATOMIC_RELAXED,
                                                 __HIP_MEMORY_SCOPE_AGENT);
            }
        }

        // ---- stage own quarter into the hi plane (wave-private cols) ----
#pragma unroll
        for (int j = 0; j < 16; ++j) {
            const int c = qcol + ((j >> 2) << 6) + l;
            Hhi[j & 3][c] = (ushort_t)(v[j] >> 16);
        }
        asm volatile("s_waitcnt lgkmcnt(0)" ::: "memory");
        __builtin_amdgcn_sched_barrier(0);

        // ---- MFMA: wave w does K-quarter [256w,256w+256), 4 col-tiles ----
        f32x4 acc[4];
#pragma unroll
        for (int i = 0; i < 4; ++i) { acc[i][0]=0.f; acc[i][1]=0.f; acc[i][2]=0.f; acc[i][3]=0.f; }
        {
            const int kbase = qcol + lg * 8;
            const ushort_t* ph = &Hhi[lm & 3][kbase];
            const ushort_t* pw = &Ws[lm][kbase];
#pragma unroll
            for (int kk = 0; kk < 256; kk += 32) {
                const frag16 ahi = *(const frag16*)(ph + kk);
#pragma unroll
                for (int tl = 0; tl < 4; ++tl) {
                    const frag16 wf = *(const frag16*)(pw + (size_t)tl * 16 * WSTR + kk);
                    acc[tl] = __builtin_amdgcn_mfma_f32_16x16x32_bf16(ahi, wf, acc[tl], 0, 0, 0);
                }
            }
        }
        // acc rows are batch-replicated across lg (row=lg*4+q => batch q):
        // lane(lm,lg) writes tile tl=lg -> 4 LDS writes/lane.
#pragma unroll
        for (int q = 0; q < 4; ++q)
            Cred[t & 1][w][lg][q][lm] = acc[lg][q];
        lds_barrier();

        // ---- finish: all 64 lanes; lane(lm,lg) owns (batch bq, col jcol) ----
        const float s = (Cred[t & 1][0][w][lg][lm] + Cred[t & 1][1][w][lg][lm])
                      + (Cred[t & 1][2][w][lg][lm] + Cred[t & 1][3][w][lg][lm]);
        const float hv = fast_tanh(s + xpv);
        const uint_t pk = ((uint_t)f2b(hv) << 16)
                        | (uint_t)(t + 1);   // tag t+1, never 0

        // ---- pre-issue next-step gather + XP BEFORE the store ----
        if (t + 1 < SEQ) {
            const uint_t* base = Hbuf + (size_t)(t & 1) * 65536;
#pragma unroll
            for (int j = 0; j < 16; ++j)
                v[j] = __hip_atomic_load(&base[goff[j]], __ATOMIC_RELAXED,
                                         __HIP_MEMORY_SCOPE_AGENT);
            xpn = XP[(size_t)((bq) * SEQ + (t + 1)) * HID + jcol];
        }
        __hip_atomic_store(&Hbuf[((size_t)(t & 1) * 64 + bq) * 1024 + jcol], pk,
                           __ATOMIC_RELAXED, __HIP_MEMORY_SCOPE_AGENT);
        // no trailing barrier: stage writes are wave-private, Cred is
        // ping-ponged by t&1, global slot reuse is gated by the spin.
    }
}

// ---------------- Phase 3: Out[b][n] = sum_k H[b,k]*Who[n,k] + bho[n] ----------
// H arrives as tagged u32 (bf16 in high half).
__global__ __launch_bounds__(256)
void outproj_kernel(const uint_t* __restrict__ Hp, const float* __restrict__ Who,
                    const float* __restrict__ bho, float* __restrict__ Out)
{
    const int tid = (int)threadIdx.x;
    const int w = tid >> 6, l = tid & 63;
    const int lm = l & 15, lg = l >> 4, hk = lg * 8;
    const int n0 = (int)blockIdx.x * 64;

    f32x4 acc[4];
#pragma unroll
    for (int i = 0; i < 4; ++i) { acc[i][0]=0.f; acc[i][1]=0.f; acc[i][2]=0.f; acc[i][3]=0.f; }

    for (int k0 = 0; k0 < HID; k0 += 32) {
        const uint_t* hr = Hp + (size_t)(w*16 + lm) * HID + k0 + hk;
        frag16 ahi;
#pragma unroll
        for (int j = 0; j < 8; ++j)
            ahi[j] = (short)(hr[j] >> 16);
#pragma unroll
        for (int bi = 0; bi < 4; ++bi) {
            const u16x8 bv = cvt8_hi(&Who[(size_t)(n0 + bi*16 + lm) * HID + k0 + hk]);
            acc[bi] = __builtin_amdgcn_mfma_f32_16x16x32_bf16(ahi, (frag16)bv, acc[bi], 0, 0, 0);
        }
    }
#pragma unroll
    for (int bi = 0; bi < 4; ++bi) {
        const int n = n0 + bi*16 + lm;
        const float bias = bho[n];
#pragma unroll
        for (int q = 0; q < 4; ++q) {
            const int b = w*16 + lg*4 + q;
            Out[(size_t)b * OUTF + n] = acc[bi][q] + bias;
        }
    }
}

// ---------------- launcher -----------------------------------------------------
extern "C" void kernel_launch(void* const* d_in, const int* in_sizes, int n_in,
                              void* d_out, int out_size, void* d_ws, size_t ws_size,
                              hipStream_t stream)
{
    const float* X   = (const float*)d_in[0];
    const float* Wih = (const float*)d_in[1];
    const float* bih = (const float*)d_in[2];
    const float* Whh = (const float*)d_in[3];
    const float* bhh = (const float*)d_in[4];
    const float* Who = (const float*)d_in[5];
    const float* bho = (const float*)d_in[6];
    float* Out = (float*)d_out;

    char* ws = (char*)d_ws;
    float* XP = (float*)ws;                                        // 128 MiB
    uint_t* Hbuf = (uint_t*)(ws + (size_t)32768 * 1024 * 4);       // 512 KiB
    // No memset needed: tags are t+1 (1..512) in the low 16 bits; 0xAAAA
    // poison and zeros never match a tag.

    xproj_kernel<<<dim3(256, 8), dim3(256), 0, stream>>>(X, Wih, bih, bhh, XP);

    rnn_scan_kernel<<<dim3(256), dim3(256), 0, stream>>>(XP, Whh, Hbuf);

    // SEQ=512 -> final step t=511 wrote buffer (511 & 1) = 1
    outproj_kernel<<<dim3(OUTF / 64), dim3(256), 0, stream>>>(Hbuf + (size_t)65536,
                                                              Who, bho, Out);
}